// Round 10
// baseline (3465.899 us; speedup 1.0000x reference)
//
#include <hip/hip_runtime.h>

#define T_STEPS 784
#define H 512
#define NBATCH 128
#define OUTC 10
#define CHUNK 32
#define NCH 25   // 24 full chunks of 32 + tail of 16

// out layout (floats): outputs[128*10] | fr1[128*512] | fr2 | fr3 | layer_fr[3]
#define OFF_OUT   0
#define OFF_FR1   1280
#define OFF_FR2   66816
#define OFF_FR3   132352
#define OFF_LFR   197888

typedef unsigned long long u64;

// Per-sample bit-exchange unit: 784*8 = 6272 u64, stride 6400 u64 (51.2 KB).
// Carved from dead input buffers (free after prep; harness restores each launch):
// W2: 131072 u64 -> 20 units | W3: 20 | m1: 200704 u64 -> 31 | m2: 31 | m3: 31
__device__ __forceinline__ u64* unit_ptr(int n, u64* W2m, u64* W3m,
                                         u64* m1m, u64* m2m, u64* m3m)
{
    if (n < 20)  return W2m + n * 6400;
    if (n < 40)  return W3m + (n - 20) * 6400;
    if (n < 71)  return m1m + (n - 40) * 6400;
    if (n < 102) return m2m + (n - 71) * 6400;
    return m3m + (n - 102) * 6400;
}

__global__ __launch_bounds__(256) void prep_kernel(
    const float* __restrict__ W2, const float* __restrict__ W3,
    const float* __restrict__ m1, const float* __restrict__ m2, const float* __restrict__ m3,
    float* __restrict__ W2T, float* __restrict__ W3T,
    unsigned char* __restrict__ mP, int* __restrict__ flags,
    float* __restrict__ out_tail)
{
    int tid = blockIdx.x * blockDim.x + threadIdx.x;
    int stride = gridDim.x * blockDim.x;
    for (int p = tid; p < H * H; p += stride) {
        int i = p >> 9, j = p & (H - 1);
        W2T[p] = W2[j * H + i];
        W3T[p] = W3[j * H + i];
    }
    for (int p = tid; p < T_STEPS * H; p += stride) {
        int t = p >> 9, i = p & (H - 1);
        unsigned char b = 0;
        if (m1[i * T_STEPS + t] != 0.f) b |= 1;
        if (m2[i * T_STEPS + t] != 0.f) b |= 2;
        if (m3[i * T_STEPS + t] != 0.f) b |= 4;
        mP[p] = b;
    }
    if (tid < NBATCH) flags[tid] = 0;
    if (tid < 3) out_tail[tid] = 0.f;
}

// gather all set bits of one ballot word; row loads independent -> pipeline
#define GWORD(WRD, IB, WT) { \
    u64 w_ = (WRD); \
    while (w_) { \
        int b_ = __builtin_ctzll(w_); \
        w_ &= w_ - 1ull; \
        const float* rp_ = (WT) + (((IB) + b_) << 9); \
        float4 v0_ = *(const float4*)(rp_ + (lane << 2)); \
        float4 v1_ = *(const float4*)(rp_ + 256 + (lane << 2)); \
        a0.x += v0_.x; a0.y += v0_.y; a0.z += v0_.z; a0.w += v0_.w; \
        a1.x += v1_.x; a1.y += v1_.y; a1.z += v1_.z; a1.w += v1_.w; \
    } }

#define GATHER_CHUNK(WT) \
    for (int q = 0; q < per; ++q) { \
        const int tl = wid * per + q; \
        const int t = tb + tl; \
        u64 bw0 = BMbuf[t][0], bw1 = BMbuf[t][1]; \
        u64 bw2 = BMbuf[t][2], bw3 = BMbuf[t][3]; \
        u64 bw4 = BMbuf[t][4], bw5 = BMbuf[t][5]; \
        u64 bw6 = BMbuf[t][6], bw7 = BMbuf[t][7]; \
        float4 a0 = make_float4(0.f, 0.f, 0.f, 0.f); \
        float4 a1 = make_float4(0.f, 0.f, 0.f, 0.f); \
        GWORD(bw0,   0, WT) GWORD(bw1,  64, WT) \
        GWORD(bw2, 128, WT) GWORD(bw3, 192, WT) \
        GWORD(bw4, 256, WT) GWORD(bw5, 320, WT) \
        GWORD(bw6, 384, WT) GWORD(bw7, 448, WT) \
        *(float4*)&Ibuf[tl][lane << 2] = a0; \
        *(float4*)&Ibuf[tl][256 + (lane << 2)] = a1; \
    }

__global__ __launch_bounds__(1024) void snn_kernel(
    const float* __restrict__ x,
    const float* __restrict__ W1, const float* __restrict__ b1,
    const float* __restrict__ b2, const float* __restrict__ b3,
    const float* __restrict__ W4, const float* __restrict__ b4,
    const float* __restrict__ W2T, const float* __restrict__ W3T,
    const unsigned char* __restrict__ mP,
    u64* W2m, u64* W3m, u64* m1m, u64* m2m, u64* m3m,
    int* flags, float* __restrict__ out)
{
    const int bid = blockIdx.x;
    const int n = bid >> 1;
    const int role = bid & 1;      // 0 = A (layers 1+2, producer), 1 = B (layer 3 + head)
    const int tid = threadIdx.x;
    const int lane = tid & 63;
    const int wid = tid >> 6;      // 0..15
    const bool upd = tid < H;
    const int j = tid;

    __shared__ u64 BMbuf[T_STEPS][8];    // 50 KB spike bits
    __shared__ float Ibuf[CHUNK][H];     // 64 KB gathered inputs, one chunk
    __shared__ float x_lds[T_STEPS];
    __shared__ float acc10[16];
    __shared__ float rsum[4];

    u64* gb = unit_ptr(n, W2m, W3m, m1m, m2m, m3m);
    const float inv_t = 1.f / (float)T_STEPS;
    const float sc = 1.f / ((float)NBATCH * (float)H * (float)T_STEPS);

    if (role == 0) {
        // ================= block A: pass 1 + layer 2, publish s2 bits =================
        for (int t = tid; t < T_STEPS; t += 1024) x_lds[t] = x[n * T_STEPS + t];
        float mem1 = 0.f, s1 = 0.f, c1 = 0.f;
        float mem2 = 0.f, s2 = 0.f, c2 = 0.f;
        float w1 = 0.f, b1v = 0.f, b2v = 0.f;
        if (upd) { w1 = W1[j]; b1v = b1[j]; b2v = b2[j]; }
        __syncthreads();   // x_lds ready

        // ---- pass 1: layer-1 recurrence over all T; s1 bits -> BMbuf
        if (upd) {
            unsigned char cur[8];
            #pragma unroll
            for (int q = 0; q < 8; ++q) cur[q] = mP[q * H + j];
            for (int g = 0; g < 98; ++g) {
                const int tb8 = g << 3;
                unsigned char nxt[8];
                #pragma unroll
                for (int q = 0; q < 8; ++q) {
                    int tnx = tb8 + 8 + q;
                    if (tnx > T_STEPS - 1) tnx = T_STEPS - 1;
                    nxt[q] = mP[tnx * H + j];
                }
                #pragma unroll
                for (int q = 0; q < 8; ++q) {
                    const int t = tb8 + q;
                    const bool k1 = (cur[q] & 1) != 0;
                    float nm = mem1 * (0.2f * (1.f - s1)) + x_lds[t] * w1 + b1v;
                    if (k1) mem1 = nm;
                    const bool f1 = k1 && (mem1 > 0.5f);
                    s1 = f1 ? 1.f : 0.f;  c1 += s1;
                    u64 ball = __ballot(f1);
                    if (lane == 0) BMbuf[t][wid] = ball;
                    cur[q] = nxt[q];
                }
            }
        }

        // ---- layer-2 chunks: gather (s1 bits) -> scan -> publish s2 bits
        for (int ch = 0; ch < NCH; ++ch) {
            const int tb = ch * CHUNK;
            const int Cc = (T_STEPS - tb < CHUNK) ? (T_STEPS - tb) : CHUNK;
            const int per = Cc >> 4;
            __syncthreads();   // BMbuf(s1) final / Ibuf free
            GATHER_CHUNK(W2T)
            __syncthreads();   // Ibuf ready
            if (upd) {
                const int ngr = Cc >> 3;
                unsigned char mcur[8]; float scur[8];
                #pragma unroll
                for (int q = 0; q < 8; ++q) { mcur[q] = mP[(tb + q) * H + j]; scur[q] = Ibuf[q][j]; }
                for (int g = 0; g < ngr; ++g) {
                    unsigned char mnx[8]; float snx[8];
                    const int nb = (g + 1) << 3;
                    const int pb = (nb < Cc) ? nb : (g << 3);
                    #pragma unroll
                    for (int q = 0; q < 8; ++q) { mnx[q] = mP[(tb + pb + q) * H + j]; snx[q] = Ibuf[pb + q][j]; }
                    #pragma unroll
                    for (int q = 0; q < 8; ++q) {
                        const int t = tb + (g << 3) + q;
                        const bool k = (mcur[q] & 2) != 0;
                        float nm = mem2 * (0.2f * (1.f - s2)) + scur[q] + b2v;
                        if (k) mem2 = nm;
                        const bool f = k && (mem2 > 0.5f);
                        s2 = f ? 1.f : 0.f;  c2 += s2;
                        u64 ball = __ballot(f);
                        if (lane == 0) gb[t * 8 + wid] = ball;
                        mcur[q] = mnx[q];  scur[q] = snx[q];
                    }
                }
            }
            __threadfence();   // own bit stores device-visible
            __syncthreads();
            if (tid == 0)
                __hip_atomic_store(&flags[n], ch + 1, __ATOMIC_RELEASE,
                                   __HIP_MEMORY_SCOPE_AGENT);
        }

        // ---- epilogue A: fr1, fr2, layer_fr[0..1]
        if (upd) {
            out[OFF_FR1 + n * H + j] = c1 * inv_t;
            out[OFF_FR2 + n * H + j] = c2 * inv_t;
        }
        if (tid < 4) rsum[tid] = 0.f;
        __syncthreads();
        if (upd) {
            float v1 = c1, v2 = c2;
            for (int m = 32; m; m >>= 1) { v1 += __shfl_xor(v1, m, 64); v2 += __shfl_xor(v2, m, 64); }
            if (lane == 0) { atomicAdd(&rsum[0], v1); atomicAdd(&rsum[1], v2); }
        }
        __syncthreads();
        if (tid == 0) {
            atomicAdd(&out[OFF_LFR + 0], rsum[0] * sc);
            atomicAdd(&out[OFF_LFR + 1], rsum[1] * sc);
        }
    } else {
        // ================= block B: layer 3 + output head, consumes s2 bits =================
        float mem3 = 0.f, s3 = 0.f, c3 = 0.f, b3v = 0.f;
        if (upd) b3v = b3[j];

        for (int ch = 0; ch < NCH; ++ch) {
            const int tb = ch * CHUNK;
            const int Cc = (T_STEPS - tb < CHUNK) ? (T_STEPS - tb) : CHUNK;
            const int per = Cc >> 4;
            if (tid == 0) {
                int guard = 0;
                while (__hip_atomic_load(&flags[n], __ATOMIC_ACQUIRE,
                                         __HIP_MEMORY_SCOPE_AGENT) < ch + 1) {
                    __builtin_amdgcn_s_sleep(1);
                    if (++guard > (1 << 24)) break;   // bounded: never hang
                }
            }
            __syncthreads();   // flag observed; also fences prior scan's Ibuf reads
            __threadfence();   // reader-side invalidate before bit loads
            for (int i = tid; i < Cc * 8; i += 1024)
                BMbuf[tb + (i >> 3)][i & 7] = gb[tb * 8 + i];
            __syncthreads();   // s2 bits in LDS
            GATHER_CHUNK(W3T)
            __syncthreads();   // Ibuf ready
            if (upd) {
                const int ngr = Cc >> 3;
                unsigned char mcur[8]; float scur[8];
                #pragma unroll
                for (int q = 0; q < 8; ++q) { mcur[q] = mP[(tb + q) * H + j]; scur[q] = Ibuf[q][j]; }
                for (int g = 0; g < ngr; ++g) {
                    unsigned char mnx[8]; float snx[8];
                    const int nb = (g + 1) << 3;
                    const int pb = (nb < Cc) ? nb : (g << 3);
                    #pragma unroll
                    for (int q = 0; q < 8; ++q) { mnx[q] = mP[(tb + pb + q) * H + j]; snx[q] = Ibuf[pb + q][j]; }
                    #pragma unroll
                    for (int q = 0; q < 8; ++q) {
                        const bool k = (mcur[q] & 4) != 0;
                        float nm = mem3 * (0.2f * (1.f - s3)) + scur[q] + b3v;
                        if (k) mem3 = nm;
                        const bool f = k && (mem3 > 0.5f);
                        s3 = f ? 1.f : 0.f;  c3 += s3;
                        mcur[q] = mnx[q];  scur[q] = snx[q];
                    }
                }
            }
        }

        // ---- epilogue B: fr3, outputs (osum linear in s3), layer_fr[2]
        if (upd) out[OFF_FR3 + n * H + j] = c3 * inv_t;
        if (tid < 16) acc10[tid] = 0.f;
        if (tid < 4)  rsum[tid] = 0.f;
        __syncthreads();
        if (upd) {
            for (int o = 0; o < OUTC; ++o) {
                float v = c3 * W4[o * H + j];
                for (int m = 32; m; m >>= 1) v += __shfl_xor(v, m, 64);
                if (lane == 0) atomicAdd(&acc10[o], v);
            }
            float v3 = c3;
            for (int m = 32; m; m >>= 1) v3 += __shfl_xor(v3, m, 64);
            if (lane == 0) atomicAdd(&rsum[2], v3);
        }
        __syncthreads();
        if (tid < OUTC) out[OFF_OUT + n * OUTC + tid] = acc10[tid] * inv_t + b4[tid];
        if (tid == 0) atomicAdd(&out[OFF_LFR + 2], rsum[2] * sc);
    }
}

extern "C" void kernel_launch(void* const* d_in, const int* in_sizes, int n_in,
                              void* d_out, int out_size, void* d_ws, size_t ws_size,
                              hipStream_t stream)
{
    const float* x  = (const float*)d_in[0];
    const float* W1 = (const float*)d_in[1];
    const float* b1 = (const float*)d_in[2];
    const float* W2 = (const float*)d_in[3];
    const float* b2 = (const float*)d_in[4];
    const float* W3 = (const float*)d_in[5];
    const float* b3 = (const float*)d_in[6];
    const float* W4 = (const float*)d_in[7];
    const float* b4 = (const float*)d_in[8];
    const float* m1 = (const float*)d_in[9];
    const float* m2 = (const float*)d_in[10];
    const float* m3 = (const float*)d_in[11];
    float* out = (float*)d_out;

    float* W2T = (float*)d_ws;                 // H x H
    float* W3T = W2T + H * H;                  // H x H
    unsigned char* mP = (unsigned char*)(W3T + H * H);   // 784*512 B
    int* flags = (int*)(mP + T_STEPS * H);     // 128 ints

    // bit-exchange buffers carved from dead input regions (restored each launch)
    u64* W2m = (u64*)d_in[3];
    u64* W3m = (u64*)d_in[5];
    u64* m1m = (u64*)d_in[9];
    u64* m2m = (u64*)d_in[10];
    u64* m3m = (u64*)d_in[11];

    hipLaunchKernelGGL(prep_kernel, dim3(512), dim3(256), 0, stream,
                       W2, W3, m1, m2, m3, W2T, W3T, mP, flags, out + OFF_LFR);
    hipLaunchKernelGGL(snn_kernel, dim3(2 * NBATCH), dim3(1024), 0, stream,
                       x, W1, b1, b2, b3, W4, b4, W2T, W3T, mP,
                       W2m, W3m, m1m, m2m, m3m, flags, out);
}

// Round 11
// 1439.979 us; speedup vs baseline: 2.4069x; 2.4069x over previous
//
#include <hip/hip_runtime.h>

#define T_STEPS 784
#define H 512
#define NBATCH 128
#define OUTC 10
#define CHUNK 32
#define NCH 25   // 24 full chunks of 32 + tail of 16

// out layout (floats): outputs[128*10] | fr1[128*512] | fr2 | fr3 | layer_fr[3]
#define OFF_OUT   0
#define OFF_FR1   1280
#define OFF_FR2   66816
#define OFF_FR3   132352
#define OFF_LFR   197888

typedef unsigned long long u64;
typedef __attribute__((ext_vector_type(8)))  short short8;   // 8 bf16 = 4 VGPR
typedef __attribute__((ext_vector_type(16))) float f32x16;   // MFMA 32x32 acc
typedef __attribute__((ext_vector_type(4)))  int   int4v;

__device__ __forceinline__ unsigned short f2bf(float f) {
    unsigned int u = __float_as_uint(f);
    unsigned int r = (u + 0x7FFFu + ((u >> 16) & 1u)) >> 16;   // RNE
    return (unsigned short)r;
}

// B-fragment packing for mfma_f32_32x32x16_bf16, one 512x512 weight matrix:
// Bp[kc][nt][lane][e], i = kc*16 + 8*(lane>>5) + e, n = nt*32 + (lane&31)
// value = W[n][i] split into hi = bf16(w), lo = bf16(w - hi).
__global__ __launch_bounds__(256) void prep_kernel(
    const float* __restrict__ W2, const float* __restrict__ W3,
    const float* __restrict__ m1, const float* __restrict__ m2, const float* __restrict__ m3,
    unsigned short* __restrict__ B2h, unsigned short* __restrict__ B2l,
    unsigned short* __restrict__ B3h, unsigned short* __restrict__ B3l,
    unsigned char* __restrict__ mP, float* __restrict__ out_tail)
{
    int tid = blockIdx.x * blockDim.x + threadIdx.x;
    int stride = gridDim.x * blockDim.x;
    for (int p = tid; p < H * H; p += stride) {
        int kc = p >> 13;          // 32
        int nt = (p >> 9) & 15;    // 16
        int lane = (p >> 3) & 63;  // 64
        int e = p & 7;             // 8
        int i = kc * 16 + ((lane >> 5) << 3) + e;
        int n = nt * 32 + (lane & 31);
        float w2 = W2[n * H + i];
        unsigned short h2 = f2bf(w2);
        B2h[p] = h2;
        B2l[p] = f2bf(w2 - __uint_as_float(((unsigned int)h2) << 16));
        float w3 = W3[n * H + i];
        unsigned short h3 = f2bf(w3);
        B3h[p] = h3;
        B3l[p] = f2bf(w3 - __uint_as_float(((unsigned int)h3) << 16));
    }
    for (int p = tid; p < T_STEPS * H; p += stride) {
        int t = p >> 9, i = p & (H - 1);
        unsigned char b = 0;
        if (m1[i * T_STEPS + t] != 0.f) b |= 1;
        if (m2[i * T_STEPS + t] != 0.f) b |= 2;
        if (m3[i * T_STEPS + t] != 0.f) b |= 4;
        mP[p] = b;
    }
    if (tid < 3) out_tail[tid] = 0.f;
}

// one chunk GEMM: C[32 t][512 n] = S[32 t][512 i] @ W[i][n]; wave w owns cols [32w,32w+32)
__device__ __forceinline__ void gemm_chunk(
    const short8* __restrict__ Bh, const short8* __restrict__ Bl,
    int tb, int wid, int lane,
    const u64* __restrict__ BMflat, float (*Ib)[H])
{
    const u64* bp = BMflat + (tb + (lane & 31)) * 8;
    u64 bw0 = bp[0], bw1 = bp[1], bw2 = bp[2], bw3 = bp[3];
    u64 bw4 = bp[4], bw5 = bp[5], bw6 = bp[6], bw7 = bp[7];
    f32x16 Ch = {0.f};
    f32x16 Cl = {0.f};
    const short8* ph = Bh + (wid << 6) + lane;   // + kc*1024 per k-step
    const short8* pl = Bl + (wid << 6) + lane;
    const int gsh = (lane >> 5) << 3;            // 0 or 8
#define KSTEP(KC, BW) { \
        unsigned int byte = (unsigned int)((BW >> (((KC) & 3) * 16 + gsh)) & 0xFFull); \
        int c01 = ((byte & 1u)  ? 0x3F80 : 0) | ((byte & 2u)   ? 0x3F800000 : 0); \
        int c23 = ((byte & 4u)  ? 0x3F80 : 0) | ((byte & 8u)   ? 0x3F800000 : 0); \
        int c45 = ((byte & 16u) ? 0x3F80 : 0) | ((byte & 32u)  ? 0x3F800000 : 0); \
        int c67 = ((byte & 64u) ? 0x3F80 : 0) | ((byte & 128u) ? 0x3F800000 : 0); \
        int4v av = {c01, c23, c45, c67}; \
        short8 a = __builtin_bit_cast(short8, av); \
        short8 bhf = ph[(KC) << 10]; \
        short8 blf = pl[(KC) << 10]; \
        Ch = __builtin_amdgcn_mfma_f32_32x32x16_bf16(a, bhf, Ch, 0, 0, 0); \
        Cl = __builtin_amdgcn_mfma_f32_32x32x16_bf16(a, blf, Cl, 0, 0, 0); \
    }
    KSTEP(0, bw0)  KSTEP(1, bw0)  KSTEP(2, bw0)  KSTEP(3, bw0)
    KSTEP(4, bw1)  KSTEP(5, bw1)  KSTEP(6, bw1)  KSTEP(7, bw1)
    KSTEP(8, bw2)  KSTEP(9, bw2)  KSTEP(10, bw2) KSTEP(11, bw2)
    KSTEP(12, bw3) KSTEP(13, bw3) KSTEP(14, bw3) KSTEP(15, bw3)
    KSTEP(16, bw4) KSTEP(17, bw4) KSTEP(18, bw4) KSTEP(19, bw4)
    KSTEP(20, bw5) KSTEP(21, bw5) KSTEP(22, bw5) KSTEP(23, bw5)
    KSTEP(24, bw6) KSTEP(25, bw6) KSTEP(26, bw6) KSTEP(27, bw6)
    KSTEP(28, bw7) KSTEP(29, bw7) KSTEP(30, bw7) KSTEP(31, bw7)
#undef KSTEP
    const int col = (wid << 5) + (lane & 31);
    const int rb = (lane >> 5) << 2;
    #pragma unroll
    for (int r = 0; r < 16; ++r)
        Ib[(r & 3) + ((r >> 2) << 3) + rb][col] = Ch[r] + Cl[r];
}

__global__ __launch_bounds__(1024) void snn_kernel(
    const float* __restrict__ x,
    const float* __restrict__ W1, const float* __restrict__ b1,
    const float* __restrict__ b2, const float* __restrict__ b3,
    const float* __restrict__ W4, const float* __restrict__ b4,
    const short8* __restrict__ B2h, const short8* __restrict__ B2l,
    const short8* __restrict__ B3h, const short8* __restrict__ B3l,
    const unsigned char* __restrict__ mP,
    float* __restrict__ out)
{
    const int n = blockIdx.x;
    const int tid = threadIdx.x;
    const int lane = tid & 63;
    const int wid = tid >> 6;      // 0..15
    const bool upd = tid < H;
    const int j = tid;

    __shared__ u64 BMbuf[T_STEPS][8];    // 50 KB spike bits (per layer, in place)
    __shared__ float Ibuf[CHUNK][H];     // 64 KB chunk inputs
    __shared__ float x_lds[T_STEPS];
    __shared__ float acc10[16];
    __shared__ float rsum[3];

    for (int t = tid; t < T_STEPS; t += 1024) x_lds[t] = x[n * T_STEPS + t];

    float mem1 = 0.f, s1 = 0.f, c1 = 0.f;
    float mem2 = 0.f, s2 = 0.f, c2 = 0.f;
    float mem3 = 0.f, s3 = 0.f, c3 = 0.f;
    float w1 = 0.f, b1v = 0.f, b2v = 0.f, b3v = 0.f;
    if (upd) { w1 = W1[j]; b1v = b1[j]; b2v = b2[j]; b3v = b3[j]; }

    __syncthreads();   // x_lds ready

    // ---- Pass 1: layer-1 elementwise recurrence; s1 bits -> BMbuf
    if (upd) {
        unsigned char cur[8];
        #pragma unroll
        for (int q = 0; q < 8; ++q) cur[q] = mP[q * H + j];
        for (int g = 0; g < 98; ++g) {
            const int tb8 = g << 3;
            unsigned char nxt[8];
            #pragma unroll
            for (int q = 0; q < 8; ++q) {
                int tnx = tb8 + 8 + q;
                if (tnx > T_STEPS - 1) tnx = T_STEPS - 1;
                nxt[q] = mP[tnx * H + j];
            }
            #pragma unroll
            for (int q = 0; q < 8; ++q) {
                const int t = tb8 + q;
                const bool k1 = (cur[q] & 1) != 0;
                float nm = mem1 * (0.2f * (1.f - s1)) + x_lds[t] * w1 + b1v;
                if (k1) mem1 = nm;
                const bool f1 = k1 && (mem1 > 0.5f);
                s1 = f1 ? 1.f : 0.f;  c1 += s1;
                u64 ball = __ballot(f1);
                if (lane == 0) BMbuf[t][wid] = ball;
                cur[q] = nxt[q];
            }
        }
    }

#define SCAN_CHUNK(LMASK, MEMV, SV, CV, BV, WRITE_BITS) \
    if (upd) { \
        const int ngr = Cc >> 3; \
        unsigned char mcur[8]; float scur[8]; \
        _Pragma("unroll") \
        for (int q = 0; q < 8; ++q) { mcur[q] = mP[(tb + q) * H + j]; scur[q] = Ibuf[q][j]; } \
        for (int g = 0; g < ngr; ++g) { \
            unsigned char mnx[8]; float snx[8]; \
            const int nb = (g + 1) << 3; \
            const int pb = (nb < Cc) ? nb : (g << 3); \
            _Pragma("unroll") \
            for (int q = 0; q < 8; ++q) { mnx[q] = mP[(tb + pb + q) * H + j]; snx[q] = Ibuf[pb + q][j]; } \
            _Pragma("unroll") \
            for (int q = 0; q < 8; ++q) { \
                const int t = tb + (g << 3) + q; \
                const bool k_ = (mcur[q] & (LMASK)) != 0; \
                float nm_ = MEMV * (0.2f * (1.f - SV)) + scur[q] + BV; \
                if (k_) MEMV = nm_; \
                const bool f_ = k_ && (MEMV > 0.5f); \
                SV = f_ ? 1.f : 0.f;  CV += SV; \
                if (WRITE_BITS) { u64 ball_ = __ballot(f_); if (lane == 0) BMbuf[t][wid] = ball_; } \
                mcur[q] = mnx[q];  scur[q] = snx[q]; \
            } \
        } \
    }

    // ---- Pass 2: layer 2 = chunk GEMM (s1 bits) + scan (writes s2 bits)
    for (int ch = 0; ch < NCH; ++ch) {
        const int tb = ch * CHUNK;
        const int Cc = (T_STEPS - tb < CHUNK) ? (T_STEPS - tb) : CHUNK;
        __syncthreads();   // Ibuf free / BMbuf final
        gemm_chunk(B2h, B2l, tb, wid, lane, &BMbuf[0][0], Ibuf);
        __syncthreads();   // Ibuf ready
        SCAN_CHUNK(2, mem2, s2, c2, b2v, 1)
    }

    // ---- Pass 3: layer 3 = chunk GEMM (s2 bits) + scan (no bit writes)
    for (int ch = 0; ch < NCH; ++ch) {
        const int tb = ch * CHUNK;
        const int Cc = (T_STEPS - tb < CHUNK) ? (T_STEPS - tb) : CHUNK;
        __syncthreads();   // Ibuf free / BMbuf(s2) final
        gemm_chunk(B3h, B3l, tb, wid, lane, &BMbuf[0][0], Ibuf);
        __syncthreads();   // Ibuf ready
        SCAN_CHUNK(4, mem3, s3, c3, b3v, 0)
    }

    __syncthreads();

    // ---- epilogue ----
    const float inv_t = 1.f / (float)T_STEPS;
    if (upd) {
        out[OFF_FR1 + n * H + j] = c1 * inv_t;
        out[OFF_FR2 + n * H + j] = c2 * inv_t;
        out[OFF_FR3 + n * H + j] = c3 * inv_t;
    }
    if (tid < 16) acc10[tid] = 0.f;
    if (tid < 3)  rsum[tid] = 0.f;
    __syncthreads();

    if (upd) {
        for (int o = 0; o < OUTC; ++o) {
            float v = c3 * W4[o * H + j];
            for (int m = 32; m; m >>= 1) v += __shfl_xor(v, m, 64);
            if (lane == 0) atomicAdd(&acc10[o], v);
        }
        float v1 = c1, v2 = c2, v3 = c3;
        for (int m = 32; m; m >>= 1) {
            v1 += __shfl_xor(v1, m, 64);
            v2 += __shfl_xor(v2, m, 64);
            v3 += __shfl_xor(v3, m, 64);
        }
        if (lane == 0) {
            atomicAdd(&rsum[0], v1);
            atomicAdd(&rsum[1], v2);
            atomicAdd(&rsum[2], v3);
        }
    }
    __syncthreads();
    if (tid < OUTC) out[OFF_OUT + n * OUTC + tid] = acc10[tid] * inv_t + b4[tid];
    if (tid == 0) {
        const float sc = 1.f / ((float)NBATCH * (float)H * (float)T_STEPS);
        atomicAdd(&out[OFF_LFR + 0], rsum[0] * sc);
        atomicAdd(&out[OFF_LFR + 1], rsum[1] * sc);
        atomicAdd(&out[OFF_LFR + 2], rsum[2] * sc);
    }
}

extern "C" void kernel_launch(void* const* d_in, const int* in_sizes, int n_in,
                              void* d_out, int out_size, void* d_ws, size_t ws_size,
                              hipStream_t stream)
{
    const float* x  = (const float*)d_in[0];
    const float* W1 = (const float*)d_in[1];
    const float* b1 = (const float*)d_in[2];
    const float* W2 = (const float*)d_in[3];
    const float* b2 = (const float*)d_in[4];
    const float* W3 = (const float*)d_in[5];
    const float* b3 = (const float*)d_in[6];
    const float* W4 = (const float*)d_in[7];
    const float* b4 = (const float*)d_in[8];
    const float* m1 = (const float*)d_in[9];
    const float* m2 = (const float*)d_in[10];
    const float* m3 = (const float*)d_in[11];
    float* out = (float*)d_out;

    // ws: B2h | B2l | B3h | B3l (512 KB each, MFMA-fragment order) | mP (392 KB)
    unsigned short* B2h = (unsigned short*)d_ws;
    unsigned short* B2l = B2h + H * H;
    unsigned short* B3h = B2l + H * H;
    unsigned short* B3l = B3h + H * H;
    unsigned char* mP = (unsigned char*)(B3l + H * H);

    hipLaunchKernelGGL(prep_kernel, dim3(512), dim3(256), 0, stream,
                       W2, W3, m1, m2, m3, B2h, B2l, B3h, B3l, mP, out + OFF_LFR);
    hipLaunchKernelGGL(snn_kernel, dim3(NBATCH), dim3(1024), 0, stream,
                       x, W1, b1, b2, b3, W4, b4,
                       (const short8*)B2h, (const short8*)B2l,
                       (const short8*)B3h, (const short8*)B3l, mP, out);
}

// Round 12
// 1436.054 us; speedup vs baseline: 2.4135x; 1.0027x over previous
//
#include <hip/hip_runtime.h>

#define T_STEPS 784
#define H 512
#define NBATCH 128
#define OUTC 10
#define CHUNK 32
#define NCH 25   // 24 full chunks of 32 + tail of 16
#define BMS 9    // padded BMbuf row stride (u64) — kills 16-way bank conflict

// out layout (floats): outputs[128*10] | fr1[128*512] | fr2 | fr3 | layer_fr[3]
#define OFF_OUT   0
#define OFF_FR1   1280
#define OFF_FR2   66816
#define OFF_FR3   132352
#define OFF_LFR   197888

typedef unsigned long long u64;
typedef __attribute__((ext_vector_type(8)))  short short8;   // 8 bf16 = 4 VGPR
typedef __attribute__((ext_vector_type(16))) float f32x16;   // MFMA 32x32 acc
typedef __attribute__((ext_vector_type(4)))  int   int4v;

__device__ __forceinline__ unsigned short f2bf(float f) {
    unsigned int u = __float_as_uint(f);
    unsigned int r = (u + 0x7FFFu + ((u >> 16) & 1u)) >> 16;   // RNE
    return (unsigned short)r;
}

// B-fragment packing for mfma_f32_32x32x16_bf16, one 512x512 weight matrix:
// Bp[kc][nt][lane][e], i = kc*16 + 8*(lane>>5) + e, n = nt*32 + (lane&31)
// value = W[n][i] split into hi = bf16(w), lo = bf16(w - hi).
__global__ __launch_bounds__(256) void prep_kernel(
    const float* __restrict__ W2, const float* __restrict__ W3,
    const float* __restrict__ m1, const float* __restrict__ m2, const float* __restrict__ m3,
    unsigned short* __restrict__ B2h, unsigned short* __restrict__ B2l,
    unsigned short* __restrict__ B3h, unsigned short* __restrict__ B3l,
    unsigned char* __restrict__ mP, float* __restrict__ out_tail)
{
    int tid = blockIdx.x * blockDim.x + threadIdx.x;
    int stride = gridDim.x * blockDim.x;
    for (int p = tid; p < H * H; p += stride) {
        int kc = p >> 13;          // 32
        int nt = (p >> 9) & 15;    // 16
        int lane = (p >> 3) & 63;  // 64
        int e = p & 7;             // 8
        int i = kc * 16 + ((lane >> 5) << 3) + e;
        int n = nt * 32 + (lane & 31);
        float w2 = W2[n * H + i];
        unsigned short h2 = f2bf(w2);
        B2h[p] = h2;
        B2l[p] = f2bf(w2 - __uint_as_float(((unsigned int)h2) << 16));
        float w3 = W3[n * H + i];
        unsigned short h3 = f2bf(w3);
        B3h[p] = h3;
        B3l[p] = f2bf(w3 - __uint_as_float(((unsigned int)h3) << 16));
    }
    for (int p = tid; p < T_STEPS * H; p += stride) {
        int t = p >> 9, i = p & (H - 1);
        unsigned char b = 0;
        if (m1[i * T_STEPS + t] != 0.f) b |= 1;
        if (m2[i * T_STEPS + t] != 0.f) b |= 2;
        if (m3[i * T_STEPS + t] != 0.f) b |= 4;
        mP[p] = b;
    }
    if (tid < 3) out_tail[tid] = 0.f;
}

// one chunk GEMM: C[32 t][512 n] = S[32 t][512 i] @ W[i][n]; wave w owns cols [32w,32w+32)
// B loads software-pipelined in groups of 4 k-steps (depth-1 prefetch).
__device__ __forceinline__ void gemm_chunk(
    const short8* __restrict__ Bh, const short8* __restrict__ Bl,
    int tb, int wid, int lane,
    const u64* __restrict__ BMflat, float (*Ib)[H])
{
    const u64* bp = BMflat + (tb + (lane & 31)) * BMS;
    f32x16 Ch = {0.f};
    f32x16 Cl = {0.f};
    const short8* ph = Bh + (wid << 6) + lane;   // + kc*1024 per k-step
    const short8* pl = Bl + (wid << 6) + lane;
    const int gsh = (lane >> 5) << 3;            // 0 or 8

    short8 h0 = ph[0 << 10], h1 = ph[1 << 10], h2 = ph[2 << 10], h3 = ph[3 << 10];
    short8 l0 = pl[0 << 10], l1 = pl[1 << 10], l2 = pl[2 << 10], l3 = pl[3 << 10];

    #pragma unroll
    for (int g = 0; g < 8; ++g) {
        short8 nh0, nh1, nh2, nh3, nl0, nl1, nl2, nl3;
        if (g < 7) {
            const int kb = (g + 1) << 2;
            nh0 = ph[(kb + 0) << 10];  nh1 = ph[(kb + 1) << 10];
            nh2 = ph[(kb + 2) << 10];  nh3 = ph[(kb + 3) << 10];
            nl0 = pl[(kb + 0) << 10];  nl1 = pl[(kb + 1) << 10];
            nl2 = pl[(kb + 2) << 10];  nl3 = pl[(kb + 3) << 10];
        }
        const u64 w = bp[g];   // ballot word covering kc = 4g..4g+3
#define DOKC(E, HH, LL) { \
        unsigned int byte = (unsigned int)((w >> ((E) * 16 + gsh)) & 0xFFull); \
        int c01 = ((byte & 1u)  ? 0x3F80 : 0) | ((byte & 2u)   ? 0x3F800000 : 0); \
        int c23 = ((byte & 4u)  ? 0x3F80 : 0) | ((byte & 8u)   ? 0x3F800000 : 0); \
        int c45 = ((byte & 16u) ? 0x3F80 : 0) | ((byte & 32u)  ? 0x3F800000 : 0); \
        int c67 = ((byte & 64u) ? 0x3F80 : 0) | ((byte & 128u) ? 0x3F800000 : 0); \
        int4v av = {c01, c23, c45, c67}; \
        short8 a = __builtin_bit_cast(short8, av); \
        Ch = __builtin_amdgcn_mfma_f32_32x32x16_bf16(a, HH, Ch, 0, 0, 0); \
        Cl = __builtin_amdgcn_mfma_f32_32x32x16_bf16(a, LL, Cl, 0, 0, 0); }
        DOKC(0, h0, l0)  DOKC(1, h1, l1)  DOKC(2, h2, l2)  DOKC(3, h3, l3)
#undef DOKC
        if (g < 7) {
            h0 = nh0; h1 = nh1; h2 = nh2; h3 = nh3;
            l0 = nl0; l1 = nl1; l2 = nl2; l3 = nl3;
        }
    }
    const int col = (wid << 5) + (lane & 31);
    const int rb = (lane >> 5) << 2;
    #pragma unroll
    for (int r = 0; r < 16; ++r)
        Ib[(r & 3) + ((r >> 2) << 3) + rb][col] = Ch[r] + Cl[r];
}

__global__ __launch_bounds__(1024) void snn_kernel(
    const float* __restrict__ x,
    const float* __restrict__ W1, const float* __restrict__ b1,
    const float* __restrict__ b2, const float* __restrict__ b3,
    const float* __restrict__ W4, const float* __restrict__ b4,
    const short8* __restrict__ B2h, const short8* __restrict__ B2l,
    const short8* __restrict__ B3h, const short8* __restrict__ B3l,
    const unsigned char* __restrict__ mP,
    float* __restrict__ out)
{
    const int n = blockIdx.x;
    const int tid = threadIdx.x;
    const int lane = tid & 63;
    const int wid = tid >> 6;      // 0..15
    const bool upd = tid < H;
    const int j = tid;

    __shared__ u64 BMbuf[T_STEPS][BMS]; // 55 KB spike bits (padded stride)
    __shared__ float Ibuf[CHUNK][H];    // 64 KB chunk inputs
    __shared__ float x_lds[T_STEPS];
    __shared__ float acc10[16];
    __shared__ float rsum[3];

    for (int t = tid; t < T_STEPS; t += 1024) x_lds[t] = x[n * T_STEPS + t];

    float mem1 = 0.f, s1 = 0.f, c1 = 0.f;
    float mem2 = 0.f, s2 = 0.f, c2 = 0.f;
    float mem3 = 0.f, s3 = 0.f, c3 = 0.f;
    float w1 = 0.f, b1v = 0.f, b2v = 0.f, b3v = 0.f;
    if (upd) { w1 = W1[j]; b1v = b1[j]; b2v = b2[j]; b3v = b3[j]; }

    __syncthreads();   // x_lds ready

    // ---- Pass 1: layer-1 elementwise recurrence; s1 bits -> BMbuf
    if (upd) {
        unsigned char cur[8];
        #pragma unroll
        for (int q = 0; q < 8; ++q) cur[q] = mP[q * H + j];
        for (int g = 0; g < 98; ++g) {
            const int tb8 = g << 3;
            unsigned char nxt[8];
            #pragma unroll
            for (int q = 0; q < 8; ++q) {
                int tnx = tb8 + 8 + q;
                if (tnx > T_STEPS - 1) tnx = T_STEPS - 1;
                nxt[q] = mP[tnx * H + j];
            }
            #pragma unroll
            for (int q = 0; q < 8; ++q) {
                const int t = tb8 + q;
                const bool k1 = (cur[q] & 1) != 0;
                float nm = mem1 * (0.2f * (1.f - s1)) + x_lds[t] * w1 + b1v;
                if (k1) mem1 = nm;
                const bool f1 = k1 && (mem1 > 0.5f);
                s1 = f1 ? 1.f : 0.f;  c1 += s1;
                u64 ball = __ballot(f1);
                if (lane == 0) BMbuf[t][wid] = ball;
                cur[q] = nxt[q];
            }
        }
    }

#define SCAN_CHUNK(LMASK, MEMV, SV, CV, BV, WRITE_BITS) \
    if (upd) { \
        const int ngr = Cc >> 3; \
        unsigned char mcur[8]; float scur[8]; \
        _Pragma("unroll") \
        for (int q = 0; q < 8; ++q) { mcur[q] = mP[(tb + q) * H + j]; scur[q] = Ibuf[q][j]; } \
        for (int g = 0; g < ngr; ++g) { \
            unsigned char mnx[8]; float snx[8]; \
            const int nb = (g + 1) << 3; \
            const int pb = (nb < Cc) ? nb : (g << 3); \
            _Pragma("unroll") \
            for (int q = 0; q < 8; ++q) { mnx[q] = mP[(tb + pb + q) * H + j]; snx[q] = Ibuf[pb + q][j]; } \
            _Pragma("unroll") \
            for (int q = 0; q < 8; ++q) { \
                const int t = tb + (g << 3) + q; \
                const bool k_ = (mcur[q] & (LMASK)) != 0; \
                float nm_ = MEMV * (0.2f * (1.f - SV)) + scur[q] + BV; \
                if (k_) MEMV = nm_; \
                const bool f_ = k_ && (MEMV > 0.5f); \
                SV = f_ ? 1.f : 0.f;  CV += SV; \
                if (WRITE_BITS) { u64 ball_ = __ballot(f_); if (lane == 0) BMbuf[t][wid] = ball_; } \
                mcur[q] = mnx[q];  scur[q] = snx[q]; \
            } \
        } \
    }

    // ---- Pass 2: layer 2 = chunk GEMM (s1 bits) + scan (writes s2 bits)
    for (int ch = 0; ch < NCH; ++ch) {
        const int tb = ch * CHUNK;
        const int Cc = (T_STEPS - tb < CHUNK) ? (T_STEPS - tb) : CHUNK;
        __syncthreads();   // Ibuf free / BMbuf final
        gemm_chunk(B2h, B2l, tb, wid, lane, &BMbuf[0][0], Ibuf);
        __syncthreads();   // Ibuf ready
        SCAN_CHUNK(2, mem2, s2, c2, b2v, 1)
    }

    // ---- Pass 3: layer 3 = chunk GEMM (s2 bits) + scan (no bit writes)
    for (int ch = 0; ch < NCH; ++ch) {
        const int tb = ch * CHUNK;
        const int Cc = (T_STEPS - tb < CHUNK) ? (T_STEPS - tb) : CHUNK;
        __syncthreads();   // Ibuf free / BMbuf(s2) final
        gemm_chunk(B3h, B3l, tb, wid, lane, &BMbuf[0][0], Ibuf);
        __syncthreads();   // Ibuf ready
        SCAN_CHUNK(4, mem3, s3, c3, b3v, 0)
    }

    __syncthreads();

    // ---- epilogue ----
    const float inv_t = 1.f / (float)T_STEPS;
    if (upd) {
        out[OFF_FR1 + n * H + j] = c1 * inv_t;
        out[OFF_FR2 + n * H + j] = c2 * inv_t;
        out[OFF_FR3 + n * H + j] = c3 * inv_t;
    }
    if (tid < 16) acc10[tid] = 0.f;
    if (tid < 3)  rsum[tid] = 0.f;
    __syncthreads();

    if (upd) {
        for (int o = 0; o < OUTC; ++o) {
            float v = c3 * W4[o * H + j];
            for (int m = 32; m; m >>= 1) v += __shfl_xor(v, m, 64);
            if (lane == 0) atomicAdd(&acc10[o], v);
        }
        float v1 = c1, v2 = c2, v3 = c3;
        for (int m = 32; m; m >>= 1) {
            v1 += __shfl_xor(v1, m, 64);
            v2 += __shfl_xor(v2, m, 64);
            v3 += __shfl_xor(v3, m, 64);
        }
        if (lane == 0) {
            atomicAdd(&rsum[0], v1);
            atomicAdd(&rsum[1], v2);
            atomicAdd(&rsum[2], v3);
        }
    }
    __syncthreads();
    if (tid < OUTC) out[OFF_OUT + n * OUTC + tid] = acc10[tid] * inv_t + b4[tid];
    if (tid == 0) {
        const float sc = 1.f / ((float)NBATCH * (float)H * (float)T_STEPS);
        atomicAdd(&out[OFF_LFR + 0], rsum[0] * sc);
        atomicAdd(&out[OFF_LFR + 1], rsum[1] * sc);
        atomicAdd(&out[OFF_LFR + 2], rsum[2] * sc);
    }
}

extern "C" void kernel_launch(void* const* d_in, const int* in_sizes, int n_in,
                              void* d_out, int out_size, void* d_ws, size_t ws_size,
                              hipStream_t stream)
{
    const float* x  = (const float*)d_in[0];
    const float* W1 = (const float*)d_in[1];
    const float* b1 = (const float*)d_in[2];
    const float* W2 = (const float*)d_in[3];
    const float* b2 = (const float*)d_in[4];
    const float* W3 = (const float*)d_in[5];
    const float* b3 = (const float*)d_in[6];
    const float* W4 = (const float*)d_in[7];
    const float* b4 = (const float*)d_in[8];
    const float* m1 = (const float*)d_in[9];
    const float* m2 = (const float*)d_in[10];
    const float* m3 = (const float*)d_in[11];
    float* out = (float*)d_out;

    // ws: B2h | B2l | B3h | B3l (512 KB each, MFMA-fragment order) | mP (392 KB)
    unsigned short* B2h = (unsigned short*)d_ws;
    unsigned short* B2l = B2h + H * H;
    unsigned short* B3h = B2l + H * H;
    unsigned short* B3l = B3h + H * H;
    unsigned char* mP = (unsigned char*)(B3l + H * H);

    hipLaunchKernelGGL(prep_kernel, dim3(512), dim3(256), 0, stream,
                       W2, W3, m1, m2, m3, B2h, B2l, B3h, B3l, mP, out + OFF_LFR);
    hipLaunchKernelGGL(snn_kernel, dim3(NBATCH), dim3(1024), 0, stream,
                       x, W1, b1, b2, b3, W4, b4,
                       (const short8*)B2h, (const short8*)B2l,
                       (const short8*)B3h, (const short8*)B3l, mP, out);
}

// Round 13
// 1116.159 us; speedup vs baseline: 3.1052x; 1.2866x over previous
//
#include <hip/hip_runtime.h>

#define T_STEPS 784
#define H 512
#define NBATCH 128
#define OUTC 10
#define CHUNK 32
#define BMS 9    // padded BMbuf row stride (u64) — bank-spread

// out layout (floats): outputs[128*10] | fr1[128*512] | fr2 | fr3 | layer_fr[3]
#define OFF_OUT   0
#define OFF_FR1   1280
#define OFF_FR2   66816
#define OFF_FR3   132352
#define OFF_LFR   197888

typedef unsigned long long u64;
typedef __attribute__((ext_vector_type(8)))  short short8;   // 8 bf16 = 4 VGPR
typedef __attribute__((ext_vector_type(16))) float f32x16;   // MFMA 32x32 acc
typedef __attribute__((ext_vector_type(4)))  int   int4v;

__device__ __forceinline__ unsigned short f2bf(float f) {
    unsigned int u = __float_as_uint(f);
    unsigned int r = (u + 0x7FFFu + ((u >> 16) & 1u)) >> 16;   // RNE
    return (unsigned short)r;
}

// B-fragment packing for mfma_f32_32x32x16_bf16 (same as R11/R12, validated):
// p = ((kc*16 + nt)*64 + lane)*8 + e ; i = kc*16 + 8*(lane>>5) + e ; n = nt*32 + (lane&31)
__global__ __launch_bounds__(256) void prep_kernel(
    const float* __restrict__ W2, const float* __restrict__ W3,
    const float* __restrict__ m1, const float* __restrict__ m2, const float* __restrict__ m3,
    unsigned short* __restrict__ B2h, unsigned short* __restrict__ B2l,
    unsigned short* __restrict__ B3h, unsigned short* __restrict__ B3l,
    unsigned char* __restrict__ mP, float* __restrict__ out_tail)
{
    int tid = blockIdx.x * blockDim.x + threadIdx.x;
    int stride = gridDim.x * blockDim.x;
    for (int p = tid; p < H * H; p += stride) {
        int kc = p >> 13;
        int nt = (p >> 9) & 15;
        int lane = (p >> 3) & 63;
        int e = p & 7;
        int i = kc * 16 + ((lane >> 5) << 3) + e;
        int n = nt * 32 + (lane & 31);
        float w2 = W2[n * H + i];
        unsigned short h2 = f2bf(w2);
        B2h[p] = h2;
        B2l[p] = f2bf(w2 - __uint_as_float(((unsigned int)h2) << 16));
        float w3 = W3[n * H + i];
        unsigned short h3 = f2bf(w3);
        B3h[p] = h3;
        B3l[p] = f2bf(w3 - __uint_as_float(((unsigned int)h3) << 16));
    }
    for (int p = tid; p < T_STEPS * H; p += stride) {
        int t = p >> 9, i = p & (H - 1);
        unsigned char b = 0;
        if (m1[i * T_STEPS + t] != 0.f) b |= 1;
        if (m2[i * T_STEPS + t] != 0.f) b |= 2;
        if (m3[i * T_STEPS + t] != 0.f) b |= 4;
        mP[p] = b;
    }
    if (tid < 3) out_tail[tid] = 0.f;
}

__global__ __launch_bounds__(1024)
__attribute__((amdgpu_waves_per_eu(4, 4)))
void snn_kernel(
    const float* __restrict__ x,
    const float* __restrict__ W1, const float* __restrict__ b1,
    const float* __restrict__ b2, const float* __restrict__ b3,
    const float* __restrict__ W4, const float* __restrict__ b4,
    const short8* __restrict__ B2h, const short8* __restrict__ B2l,
    const short8* __restrict__ B3h, const short8* __restrict__ B3l,
    const unsigned char* __restrict__ mP,
    float* __restrict__ out)
{
    const int n = blockIdx.x;
    const int tid = threadIdx.x;
    const int lane = tid & 63;
    const int wid = tid >> 6;      // 0..15
    const bool upd = tid < H;
    const int j = tid;

    __shared__ u64 BMbuf[T_STEPS][BMS]; // 55 KB spike bits (in place per layer)
    __shared__ float Ibuf[CHUNK][H];    // 64 KB chunk inputs
    __shared__ float x_lds[T_STEPS];
    __shared__ float acc10[16];
    __shared__ float rsum[3];

    for (int t = tid; t < T_STEPS; t += 1024) x_lds[t] = x[n * T_STEPS + t];

    float mem1 = 0.f, s1 = 0.f, c1 = 0.f;
    float mem2 = 0.f, s2 = 0.f, c2 = 0.f;
    float mem3 = 0.f, s3 = 0.f, c3 = 0.f;
    float w1 = 0.f, b1v = 0.f, b2v = 0.f, b3v = 0.f;
    if (upd) { w1 = W1[j]; b1v = b1[j]; b2v = b2[j]; b3v = b3[j]; }

    __syncthreads();   // x_lds ready

    // ---- Pass 1: layer-1 elementwise recurrence; s1 bits -> BMbuf
    if (upd) {
        unsigned char cur[8];
        #pragma unroll
        for (int q = 0; q < 8; ++q) cur[q] = mP[q * H + j];
        for (int g = 0; g < 98; ++g) {
            const int tb8 = g << 3;
            unsigned char nxt[8];
            #pragma unroll
            for (int q = 0; q < 8; ++q) {
                int tnx = tb8 + 8 + q;
                if (tnx > T_STEPS - 1) tnx = T_STEPS - 1;
                nxt[q] = mP[tnx * H + j];
            }
            #pragma unroll
            for (int q = 0; q < 8; ++q) {
                const int t = tb8 + q;
                const bool k1 = (cur[q] & 1) != 0;
                float nm = mem1 * (0.2f * (1.f - s1)) + x_lds[t] * w1 + b1v;
                if (k1) mem1 = nm;
                const bool f1 = k1 && (mem1 > 0.5f);
                s1 = f1 ? 1.f : 0.f;  c1 += s1;
                u64 ball = __ballot(f1);
                if (lane == 0) BMbuf[t][wid] = ball;
                cur[q] = nxt[q];
            }
        }
    }

#define AFRAG(W, E) ({ \
        unsigned int byte = (unsigned int)(((W) >> ((E) * 16 + gsh)) & 0xFFull); \
        int c01 = ((byte & 1u)  ? 0x3F80 : 0) | ((byte & 2u)   ? 0x3F800000 : 0); \
        int c23 = ((byte & 4u)  ? 0x3F80 : 0) | ((byte & 8u)   ? 0x3F800000 : 0); \
        int c45 = ((byte & 16u) ? 0x3F80 : 0) | ((byte & 32u)  ? 0x3F800000 : 0); \
        int c67 = ((byte & 64u) ? 0x3F80 : 0) | ((byte & 128u) ? 0x3F800000 : 0); \
        int4v av = {c01, c23, c45, c67}; \
        __builtin_bit_cast(short8, av); })

    // pair GEMM: C[t-tile0..1][512] over kc; B read once, feeds both t-tiles.
    // tmask=0 -> tile1 A is zero (tail). Results: C0 (hi+lo pair) + merged C1.
#define GEMM_PAIR(BhP, BlP, TB, TMASK, C0H, C0L, C1M) { \
        const u64* bp0 = &BMbuf[0][0] + ((TB) + (lane & 31)) * BMS; \
        const u64* bp1 = bp0 + 32 * BMS; \
        const short8* ph = (BhP) + (wid << 6) + lane; \
        const short8* pl = (BlP) + (wid << 6) + lane; \
        const int gsh = (lane >> 5) << 3; \
        f32x16 Ch0 = {0.f}, Cl0 = {0.f}, Ch1 = {0.f}, Cl1 = {0.f}; \
        short8 bh = ph[0], bl = pl[0]; \
        _Pragma("unroll") \
        for (int kc = 0; kc < 32; ++kc) { \
            short8 bhn, bln; \
            if (kc < 31) { bhn = ph[(kc + 1) << 10]; bln = pl[(kc + 1) << 10]; } \
            const u64 w0 = bp0[kc >> 2]; \
            const u64 w1 = bp1[kc >> 2] & (TMASK); \
            short8 a0 = AFRAG(w0, kc & 3); \
            short8 a1 = AFRAG(w1, kc & 3); \
            Ch0 = __builtin_amdgcn_mfma_f32_32x32x16_bf16(a0, bh, Ch0, 0, 0, 0); \
            Cl0 = __builtin_amdgcn_mfma_f32_32x32x16_bf16(a0, bl, Cl0, 0, 0, 0); \
            Ch1 = __builtin_amdgcn_mfma_f32_32x32x16_bf16(a1, bh, Ch1, 0, 0, 0); \
            Cl1 = __builtin_amdgcn_mfma_f32_32x32x16_bf16(a1, bl, Cl1, 0, 0, 0); \
            if (kc < 31) { bh = bhn; bl = bln; } \
        } \
        C0H = Ch0; C0L = Cl0; \
        _Pragma("unroll") \
        for (int r = 0; r < 16; ++r) C1M[r] = Ch1[r] + Cl1[r]; }

#define WRITE_C(CH, CL) { \
        const int col = (wid << 5) + (lane & 31); \
        const int rb = (lane >> 5) << 2; \
        _Pragma("unroll") \
        for (int r = 0; r < 16; ++r) \
            Ibuf[(r & 3) + ((r >> 2) << 3) + rb][col] = CH[r] + CL[r]; }

#define WRITE_C1(CM) { \
        const int col = (wid << 5) + (lane & 31); \
        const int rb = (lane >> 5) << 2; \
        _Pragma("unroll") \
        for (int r = 0; r < 16; ++r) \
            Ibuf[(r & 3) + ((r >> 2) << 3) + rb][col] = CM[r]; }

#define SCAN_CHUNK(TB, CC, LMASK, MEMV, SV, CV, BV, WRITE_BITS) \
    if (upd) { \
        const int ngr = (CC) >> 3; \
        unsigned char mcur[8]; float scur[8]; \
        _Pragma("unroll") \
        for (int q = 0; q < 8; ++q) { mcur[q] = mP[((TB) + q) * H + j]; scur[q] = Ibuf[q][j]; } \
        for (int g = 0; g < ngr; ++g) { \
            unsigned char mnx[8]; float snx[8]; \
            const int nb = (g + 1) << 3; \
            const int pb = (nb < (CC)) ? nb : (g << 3); \
            _Pragma("unroll") \
            for (int q = 0; q < 8; ++q) { mnx[q] = mP[((TB) + pb + q) * H + j]; snx[q] = Ibuf[pb + q][j]; } \
            _Pragma("unroll") \
            for (int q = 0; q < 8; ++q) { \
                const int t = (TB) + (g << 3) + q; \
                const bool k_ = (mcur[q] & (LMASK)) != 0; \
                float nm_ = MEMV * (0.2f * (1.f - SV)) + scur[q] + BV; \
                if (k_) MEMV = nm_; \
                const bool f_ = k_ && (MEMV > 0.5f); \
                SV = f_ ? 1.f : 0.f;  CV += SV; \
                if (WRITE_BITS) { u64 ball_ = __ballot(f_); if (lane == 0) BMbuf[t][wid] = ball_; } \
                mcur[q] = mnx[q];  scur[q] = snx[q]; \
            } \
        } \
    }

#define PASS(BhP, BlP, LMASK, MEMV, SV, CV, BV, WRITE_BITS) { \
    __syncthreads();  /* bits final, Ibuf free */ \
    for (int p = 0; p < 12; ++p) { \
        const int tb = p * 64; \
        f32x16 c0h, c0l, c1m; \
        GEMM_PAIR(BhP, BlP, tb, ~0ull, c0h, c0l, c1m) \
        __syncthreads();   /* prev scan done with Ibuf */ \
        WRITE_C(c0h, c0l) \
        __syncthreads(); \
        SCAN_CHUNK(tb, CHUNK, LMASK, MEMV, SV, CV, BV, WRITE_BITS) \
        __syncthreads(); \
        WRITE_C1(c1m) \
        __syncthreads(); \
        SCAN_CHUNK(tb + CHUNK, CHUNK, LMASK, MEMV, SV, CV, BV, WRITE_BITS) \
    } \
    { /* tail chunk 24: Cc = 16 */ \
        f32x16 c0h, c0l, c1m; \
        GEMM_PAIR(BhP, BlP, 768, 0ull, c0h, c0l, c1m) \
        (void)c1m; \
        __syncthreads(); \
        WRITE_C(c0h, c0l) \
        __syncthreads(); \
        SCAN_CHUNK(768, 16, LMASK, MEMV, SV, CV, BV, WRITE_BITS) \
    } }

    // ---- Pass 2: layer 2 (reads s1 bits, writes s2 bits)
    PASS(B2h, B2l, 2, mem2, s2, c2, b2v, 1)
    // ---- Pass 3: layer 3 (reads s2 bits)
    PASS(B3h, B3l, 4, mem3, s3, c3, b3v, 0)

    __syncthreads();

    // ---- epilogue ----
    const float inv_t = 1.f / (float)T_STEPS;
    if (upd) {
        out[OFF_FR1 + n * H + j] = c1 * inv_t;
        out[OFF_FR2 + n * H + j] = c2 * inv_t;
        out[OFF_FR3 + n * H + j] = c3 * inv_t;
    }
    if (tid < 16) acc10[tid] = 0.f;
    if (tid < 3)  rsum[tid] = 0.f;
    __syncthreads();

    if (upd) {
        for (int o = 0; o < OUTC; ++o) {
            float v = c3 * W4[o * H + j];
            for (int m = 32; m; m >>= 1) v += __shfl_xor(v, m, 64);
            if (lane == 0) atomicAdd(&acc10[o], v);
        }
        float v1 = c1, v2 = c2, v3 = c3;
        for (int m = 32; m; m >>= 1) {
            v1 += __shfl_xor(v1, m, 64);
            v2 += __shfl_xor(v2, m, 64);
            v3 += __shfl_xor(v3, m, 64);
        }
        if (lane == 0) {
            atomicAdd(&rsum[0], v1);
            atomicAdd(&rsum[1], v2);
            atomicAdd(&rsum[2], v3);
        }
    }
    __syncthreads();
    if (tid < OUTC) out[OFF_OUT + n * OUTC + tid] = acc10[tid] * inv_t + b4[tid];
    if (tid == 0) {
        const float sc = 1.f / ((float)NBATCH * (float)H * (float)T_STEPS);
        atomicAdd(&out[OFF_LFR + 0], rsum[0] * sc);
        atomicAdd(&out[OFF_LFR + 1], rsum[1] * sc);
        atomicAdd(&out[OFF_LFR + 2], rsum[2] * sc);
    }
}

extern "C" void kernel_launch(void* const* d_in, const int* in_sizes, int n_in,
                              void* d_out, int out_size, void* d_ws, size_t ws_size,
                              hipStream_t stream)
{
    const float* x  = (const float*)d_in[0];
    const float* W1 = (const float*)d_in[1];
    const float* b1 = (const float*)d_in[2];
    const float* W2 = (const float*)d_in[3];
    const float* b2 = (const float*)d_in[4];
    const float* W3 = (const float*)d_in[5];
    const float* b3 = (const float*)d_in[6];
    const float* W4 = (const float*)d_in[7];
    const float* b4 = (const float*)d_in[8];
    const float* m1 = (const float*)d_in[9];
    const float* m2 = (const float*)d_in[10];
    const float* m3 = (const float*)d_in[11];
    float* out = (float*)d_out;

    unsigned short* B2h = (unsigned short*)d_ws;
    unsigned short* B2l = B2h + H * H;
    unsigned short* B3h = B2l + H * H;
    unsigned short* B3l = B3h + H * H;
    unsigned char* mP = (unsigned char*)(B3l + H * H);

    hipLaunchKernelGGL(prep_kernel, dim3(512), dim3(256), 0, stream,
                       W2, W3, m1, m2, m3, B2h, B2l, B3h, B3l, mP, out + OFF_LFR);
    hipLaunchKernelGGL(snn_kernel, dim3(NBATCH), dim3(1024), 0, stream,
                       x, W1, b1, b2, b3, W4, b4,
                       (const short8*)B2h, (const short8*)B2l,
                       (const short8*)B3h, (const short8*)B3l, mP, out);
}

// Round 14
// 847.733 us; speedup vs baseline: 4.0884x; 1.3166x over previous
//
#include <hip/hip_runtime.h>

#define T_STEPS 784
#define H 512
#define NBATCH 128
#define OUTC 10
#define CHUNK 32
#define BMS 9    // padded BMbuf row stride (u64) — bank-spread

// out layout (floats): outputs[128*10] | fr1[128*512] | fr2 | fr3 | layer_fr[3]
#define OFF_OUT   0
#define OFF_FR1   1280
#define OFF_FR2   66816
#define OFF_FR3   132352
#define OFF_LFR   197888

typedef unsigned long long u64;
typedef __attribute__((ext_vector_type(8)))  short short8;   // 8 bf16 = 4 VGPR
typedef __attribute__((ext_vector_type(16))) float f32x16;   // MFMA 32x32 acc
typedef __attribute__((ext_vector_type(4)))  int   int4v;

__device__ __forceinline__ unsigned short f2bf(float f) {
    unsigned int u = __float_as_uint(f);
    unsigned int r = (u + 0x7FFFu + ((u >> 16) & 1u)) >> 16;   // RNE
    return (unsigned short)r;
}

// B-fragment packing for mfma_f32_32x32x16_bf16 (validated R11-R13):
// p = ((kc*16 + nt)*64 + lane)*8 + e ; i = kc*16 + 8*(lane>>5) + e ; n = nt*32 + (lane&31)
__global__ __launch_bounds__(256) void prep_kernel(
    const float* __restrict__ W2, const float* __restrict__ W3,
    const float* __restrict__ m1, const float* __restrict__ m2, const float* __restrict__ m3,
    unsigned short* __restrict__ B2h, unsigned short* __restrict__ B2l,
    unsigned short* __restrict__ B3h, unsigned short* __restrict__ B3l,
    unsigned char* __restrict__ mP, float* __restrict__ out_tail)
{
    int tid = blockIdx.x * blockDim.x + threadIdx.x;
    int stride = gridDim.x * blockDim.x;
    for (int p = tid; p < H * H; p += stride) {
        int kc = p >> 13;
        int nt = (p >> 9) & 15;
        int lane = (p >> 3) & 63;
        int e = p & 7;
        int i = kc * 16 + ((lane >> 5) << 3) + e;
        int n = nt * 32 + (lane & 31);
        float w2 = W2[n * H + i];
        unsigned short h2 = f2bf(w2);
        B2h[p] = h2;
        B2l[p] = f2bf(w2 - __uint_as_float(((unsigned int)h2) << 16));
        float w3 = W3[n * H + i];
        unsigned short h3 = f2bf(w3);
        B3h[p] = h3;
        B3l[p] = f2bf(w3 - __uint_as_float(((unsigned int)h3) << 16));
    }
    for (int p = tid; p < T_STEPS * H; p += stride) {
        int t = p >> 9, i = p & (H - 1);
        unsigned char b = 0;
        if (m1[i * T_STEPS + t] != 0.f) b |= 1;
        if (m2[i * T_STEPS + t] != 0.f) b |= 2;
        if (m3[i * T_STEPS + t] != 0.f) b |= 4;
        mP[p] = b;
    }
    if (tid < 3) out_tail[tid] = 0.f;
}

__global__ __launch_bounds__(1024)
__attribute__((amdgpu_waves_per_eu(4, 4)))
void snn_kernel(
    const float* __restrict__ x,
    const float* __restrict__ W1, const float* __restrict__ b1,
    const float* __restrict__ b2, const float* __restrict__ b3,
    const float* __restrict__ W4, const float* __restrict__ b4,
    const short8* __restrict__ B2h, const short8* __restrict__ B2l,
    const short8* __restrict__ B3h, const short8* __restrict__ B3l,
    const unsigned char* __restrict__ mP,
    float* __restrict__ out)
{
    const int n = blockIdx.x;
    const int tid = threadIdx.x;
    const int lane = tid & 63;
    const int wid = tid >> 6;      // 0..15
    const bool upd = tid < H;
    const int j = tid;

    __shared__ u64 BMbuf[T_STEPS][BMS]; // 55 KB spike bits (in place per layer)
    __shared__ float Ibuf[CHUNK][H];    // 64 KB chunk inputs
    __shared__ float x_lds[T_STEPS];
    __shared__ float acc10[16];
    __shared__ float rsum[3];

    for (int t = tid; t < T_STEPS; t += 1024) x_lds[t] = x[n * T_STEPS + t];

    float mem1 = 0.f, s1 = 0.f, c1 = 0.f;
    float mem2 = 0.f, s2 = 0.f, c2 = 0.f;
    float mem3 = 0.f, s3 = 0.f, c3 = 0.f;
    float w1 = 0.f, b1v = 0.f, b2v = 0.f, b3v = 0.f;
    if (upd) { w1 = W1[j]; b1v = b1[j]; b2v = b2[j]; b3v = b3[j]; }

    __syncthreads();   // x_lds ready

    // ---- Pass 1: layer-1 elementwise recurrence; s1 bits -> BMbuf
    if (upd) {
        unsigned char cur[8];
        #pragma unroll
        for (int q = 0; q < 8; ++q) cur[q] = mP[q * H + j];
        for (int g = 0; g < 98; ++g) {
            const int tb8 = g << 3;
            unsigned char nxt[8];
            #pragma unroll
            for (int q = 0; q < 8; ++q) {
                int tnx = tb8 + 8 + q;
                if (tnx > T_STEPS - 1) tnx = T_STEPS - 1;
                nxt[q] = mP[tnx * H + j];
            }
            #pragma unroll
            for (int q = 0; q < 8; ++q) {
                const int t = tb8 + q;
                const bool k1 = (cur[q] & 1) != 0;
                float nm = mem1 * (0.2f * (1.f - s1)) + x_lds[t] * w1 + b1v;
                if (k1) mem1 = nm;
                const bool f1 = k1 && (mem1 > 0.5f);
                s1 = f1 ? 1.f : 0.f;  c1 += s1;
                u64 ball = __ballot(f1);
                if (lane == 0) BMbuf[t][wid] = ball;
                cur[q] = nxt[q];
            }
        }
    }

#define AFRAG(W, E) ({ \
        unsigned int byte = (unsigned int)(((W) >> ((E) * 16 + gsh)) & 0xFFull); \
        int c01 = ((byte & 1u)  ? 0x3F80 : 0) | ((byte & 2u)   ? 0x3F800000 : 0); \
        int c23 = ((byte & 4u)  ? 0x3F80 : 0) | ((byte & 8u)   ? 0x3F800000 : 0); \
        int c45 = ((byte & 16u) ? 0x3F80 : 0) | ((byte & 32u)  ? 0x3F800000 : 0); \
        int c67 = ((byte & 64u) ? 0x3F80 : 0) | ((byte & 128u) ? 0x3F800000 : 0); \
        int4v av = {c01, c23, c45, c67}; \
        __builtin_bit_cast(short8, av); })

    // quad GEMM: 4 t-tiles (128 t) share one B sweep; hi and lo accumulate
    // into the SAME fp32 tile (C += A@Bh; C += A@Bl) — half the accumulators.
#define GEMM_QUAD(BhP, BlP, TB, C0, C1, C2, C3) { \
        const u64* bp = &BMbuf[0][0] + ((TB) + (lane & 31)) * BMS; \
        const short8* ph = (BhP) + (wid << 6) + lane; \
        const short8* pl = (BlP) + (wid << 6) + lane; \
        const int gsh = (lane >> 5) << 3; \
        short8 bh = ph[0], bl = pl[0]; \
        _Pragma("unroll") \
        for (int kc = 0; kc < 32; ++kc) { \
            short8 bhn, bln; \
            if (kc < 31) { bhn = ph[(kc + 1) << 10]; bln = pl[(kc + 1) << 10]; } \
            const u64 w0 = bp[kc >> 2]; \
            const u64 w1 = bp[32 * BMS + (kc >> 2)]; \
            const u64 w2 = bp[64 * BMS + (kc >> 2)]; \
            const u64 w3 = bp[96 * BMS + (kc >> 2)]; \
            short8 a0 = AFRAG(w0, kc & 3); \
            short8 a1 = AFRAG(w1, kc & 3); \
            short8 a2 = AFRAG(w2, kc & 3); \
            short8 a3 = AFRAG(w3, kc & 3); \
            C0 = __builtin_amdgcn_mfma_f32_32x32x16_bf16(a0, bh, C0, 0, 0, 0); \
            C1 = __builtin_amdgcn_mfma_f32_32x32x16_bf16(a1, bh, C1, 0, 0, 0); \
            C2 = __builtin_amdgcn_mfma_f32_32x32x16_bf16(a2, bh, C2, 0, 0, 0); \
            C3 = __builtin_amdgcn_mfma_f32_32x32x16_bf16(a3, bh, C3, 0, 0, 0); \
            C0 = __builtin_amdgcn_mfma_f32_32x32x16_bf16(a0, bl, C0, 0, 0, 0); \
            C1 = __builtin_amdgcn_mfma_f32_32x32x16_bf16(a1, bl, C1, 0, 0, 0); \
            C2 = __builtin_amdgcn_mfma_f32_32x32x16_bf16(a2, bl, C2, 0, 0, 0); \
            C3 = __builtin_amdgcn_mfma_f32_32x32x16_bf16(a3, bl, C3, 0, 0, 0); \
            if (kc < 31) { bh = bhn; bl = bln; } \
        } }

    // tail GEMM: single tile at t=768, only 16 valid steps (per-lane mask)
#define GEMM_TAIL(BhP, BlP, C0) { \
        const u64* bp = &BMbuf[0][0] + (768 + (lane & 31)) * BMS; \
        const u64 lmask = ((lane & 31) < 16) ? ~0ull : 0ull; \
        const short8* ph = (BhP) + (wid << 6) + lane; \
        const short8* pl = (BlP) + (wid << 6) + lane; \
        const int gsh = (lane >> 5) << 3; \
        short8 bh = ph[0], bl = pl[0]; \
        _Pragma("unroll") \
        for (int kc = 0; kc < 32; ++kc) { \
            short8 bhn, bln; \
            if (kc < 31) { bhn = ph[(kc + 1) << 10]; bln = pl[(kc + 1) << 10]; } \
            const u64 w0 = bp[kc >> 2] & lmask; \
            short8 a0 = AFRAG(w0, kc & 3); \
            C0 = __builtin_amdgcn_mfma_f32_32x32x16_bf16(a0, bh, C0, 0, 0, 0); \
            C0 = __builtin_amdgcn_mfma_f32_32x32x16_bf16(a0, bl, C0, 0, 0, 0); \
            if (kc < 31) { bh = bhn; bl = bln; } \
        } }

#define WRITE_CM(CM) { \
        const int col = (wid << 5) + (lane & 31); \
        const int rb = (lane >> 5) << 2; \
        _Pragma("unroll") \
        for (int r = 0; r < 16; ++r) \
            Ibuf[(r & 3) + ((r >> 2) << 3) + rb][col] = CM[r]; }

#define SCAN_CHUNK(TB, CC, LMASK, MEMV, SV, CV, BV, WRITE_BITS) \
    if (upd) { \
        const int ngr = (CC) >> 3; \
        unsigned char mcur[8]; float scur[8]; \
        _Pragma("unroll") \
        for (int q = 0; q < 8; ++q) { mcur[q] = mP[((TB) + q) * H + j]; scur[q] = Ibuf[q][j]; } \
        for (int g = 0; g < ngr; ++g) { \
            unsigned char mnx[8]; float snx[8]; \
            const int nb = (g + 1) << 3; \
            const int pb = (nb < (CC)) ? nb : (g << 3); \
            _Pragma("unroll") \
            for (int q = 0; q < 8; ++q) { mnx[q] = mP[((TB) + pb + q) * H + j]; snx[q] = Ibuf[pb + q][j]; } \
            _Pragma("unroll") \
            for (int q = 0; q < 8; ++q) { \
                const int t = (TB) + (g << 3) + q; \
                const bool k_ = (mcur[q] & (LMASK)) != 0; \
                float nm_ = MEMV * (0.2f * (1.f - SV)) + scur[q] + BV; \
                if (k_) MEMV = nm_; \
                const bool f_ = k_ && (MEMV > 0.5f); \
                SV = f_ ? 1.f : 0.f;  CV += SV; \
                if (WRITE_BITS) { u64 ball_ = __ballot(f_); if (lane == 0) BMbuf[t][wid] = ball_; } \
                mcur[q] = mnx[q];  scur[q] = snx[q]; \
            } \
        } \
    }

#define SUBCHUNK(CM, TB, LMASK, MEMV, SV, CV, BV, WRITE_BITS) \
        __syncthreads();   /* prev scan done with Ibuf */ \
        WRITE_CM(CM) \
        __syncthreads(); \
        SCAN_CHUNK(TB, CHUNK, LMASK, MEMV, SV, CV, BV, WRITE_BITS)

#define PASS(BhP, BlP, LMASK, MEMV, SV, CV, BV, WRITE_BITS) { \
    __syncthreads();  /* bits final, Ibuf free */ \
    for (int p = 0; p < 6; ++p) { \
        const int tb = p * 128; \
        f32x16 c0 = {0.f}, c1v = {0.f}, c2v = {0.f}, c3v = {0.f}; \
        GEMM_QUAD(BhP, BlP, tb, c0, c1v, c2v, c3v) \
        SUBCHUNK(c0,  tb,      LMASK, MEMV, SV, CV, BV, WRITE_BITS) \
        SUBCHUNK(c1v, tb + 32, LMASK, MEMV, SV, CV, BV, WRITE_BITS) \
        SUBCHUNK(c2v, tb + 64, LMASK, MEMV, SV, CV, BV, WRITE_BITS) \
        SUBCHUNK(c3v, tb + 96, LMASK, MEMV, SV, CV, BV, WRITE_BITS) \
    } \
    { /* tail: t = 768..783 */ \
        f32x16 c0 = {0.f}; \
        GEMM_TAIL(BhP, BlP, c0) \
        __syncthreads(); \
        WRITE_CM(c0) \
        __syncthreads(); \
        SCAN_CHUNK(768, 16, LMASK, MEMV, SV, CV, BV, WRITE_BITS) \
    } }

    // ---- Pass 2: layer 2 (reads s1 bits, writes s2 bits)
    PASS(B2h, B2l, 2, mem2, s2, c2, b2v, 1)
    // ---- Pass 3: layer 3 (reads s2 bits)
    PASS(B3h, B3l, 4, mem3, s3, c3, b3v, 0)

    __syncthreads();

    // ---- epilogue ----
    const float inv_t = 1.f / (float)T_STEPS;
    if (upd) {
        out[OFF_FR1 + n * H + j] = c1 * inv_t;
        out[OFF_FR2 + n * H + j] = c2 * inv_t;
        out[OFF_FR3 + n * H + j] = c3 * inv_t;
    }
    if (tid < 16) acc10[tid] = 0.f;
    if (tid < 3)  rsum[tid] = 0.f;
    __syncthreads();

    if (upd) {
        for (int o = 0; o < OUTC; ++o) {
            float v = c3 * W4[o * H + j];
            for (int m = 32; m; m >>= 1) v += __shfl_xor(v, m, 64);
            if (lane == 0) atomicAdd(&acc10[o], v);
        }
        float v1 = c1, v2 = c2, v3 = c3;
        for (int m = 32; m; m >>= 1) {
            v1 += __shfl_xor(v1, m, 64);
            v2 += __shfl_xor(v2, m, 64);
            v3 += __shfl_xor(v3, m, 64);
        }
        if (lane == 0) {
            atomicAdd(&rsum[0], v1);
            atomicAdd(&rsum[1], v2);
            atomicAdd(&rsum[2], v3);
        }
    }
    __syncthreads();
    if (tid < OUTC) out[OFF_OUT + n * OUTC + tid] = acc10[tid] * inv_t + b4[tid];
    if (tid == 0) {
        const float sc = 1.f / ((float)NBATCH * (float)H * (float)T_STEPS);
        atomicAdd(&out[OFF_LFR + 0], rsum[0] * sc);
        atomicAdd(&out[OFF_LFR + 1], rsum[1] * sc);
        atomicAdd(&out[OFF_LFR + 2], rsum[2] * sc);
    }
}

extern "C" void kernel_launch(void* const* d_in, const int* in_sizes, int n_in,
                              void* d_out, int out_size, void* d_ws, size_t ws_size,
                              hipStream_t stream)
{
    const float* x  = (const float*)d_in[0];
    const float* W1 = (const float*)d_in[1];
    const float* b1 = (const float*)d_in[2];
    const float* W2 = (const float*)d_in[3];
    const float* b2 = (const float*)d_in[4];
    const float* W3 = (const float*)d_in[5];
    const float* b3 = (const float*)d_in[6];
    const float* W4 = (const float*)d_in[7];
    const float* b4 = (const float*)d_in[8];
    const float* m1 = (const float*)d_in[9];
    const float* m2 = (const float*)d_in[10];
    const float* m3 = (const float*)d_in[11];
    float* out = (float*)d_out;

    unsigned short* B2h = (unsigned short*)d_ws;
    unsigned short* B2l = B2h + H * H;
    unsigned short* B3h = B2l + H * H;
    unsigned short* B3l = B3h + H * H;
    unsigned char* mP = (unsigned char*)(B3l + H * H);

    hipLaunchKernelGGL(prep_kernel, dim3(512), dim3(256), 0, stream,
                       W2, W3, m1, m2, m3, B2h, B2l, B3h, B3l, mP, out + OFF_LFR);
    hipLaunchKernelGGL(snn_kernel, dim3(NBATCH), dim3(1024), 0, stream,
                       x, W1, b1, b2, b3, W4, b4,
                       (const short8*)B2h, (const short8*)B2l,
                       (const short8*)B3h, (const short8*)B3l, mP, out);
}